// Round 2
// baseline (2887.493 us; speedup 1.0000x reference)
//
#include <hip/hip_runtime.h>
#include <hip/hip_bf16.h>

typedef __hip_bfloat16 bf16;
typedef __attribute__((ext_vector_type(8))) short short8;
typedef __attribute__((ext_vector_type(4))) float float4v;

__device__ __forceinline__ void gload16(const bf16* g, bf16* s) {
    __builtin_amdgcn_global_load_lds(
        (const __attribute__((address_space(1))) void*)g,
        (__attribute__((address_space(3))) void*)s, 16, 0, 0);
}

// raw barrier (no vmcnt drain) + compiler memory fence so loads/stores can't cross
#define BAR() do { asm volatile("" ::: "memory"); __builtin_amdgcn_s_barrier(); asm volatile("" ::: "memory"); } while (0)

// ---------------- small utility kernels ----------------

__global__ void k_convert_x(const float* __restrict__ in, bf16* __restrict__ out,
                            int n, int* __restrict__ cnt) {
    if (blockIdx.x == 0 && threadIdx.x < 16) cnt[threadIdx.x] = 0;
    int i = (blockIdx.x * blockDim.x + threadIdx.x) * 4;
    if (i + 3 < n) {
        float4 v = *(const float4*)(in + i);
        out[i + 0] = __float2bfloat16(v.x);
        out[i + 1] = __float2bfloat16(v.y);
        out[i + 2] = __float2bfloat16(v.z);
        out[i + 3] = __float2bfloat16(v.w);
    }
}

// in: [R,S] fp32 -> out: [S,R] bf16 (batched over z). 64x64 tile, 256 threads.
// fuse=1 (FC weights, S=6144): output row remapped to 16-col gate/val interleave.
__global__ __launch_bounds__(256) void k_transpose64(
    const float* __restrict__ in, bf16* __restrict__ out, int R, int S, int fuse) {
    __shared__ float tile[64][65];
    size_t mat = (size_t)blockIdx.z * R * S;
    int s0 = blockIdx.x * 64, r0 = blockIdx.y * 64;
    int tid = threadIdx.x;
    int rr = tid >> 4, sc = (tid & 15) * 4;
    #pragma unroll
    for (int i = 0; i < 4; ++i) {
        float4 v = *(const float4*)(in + mat + (size_t)(r0 + rr + i * 16) * S + s0 + sc);
        tile[rr + i * 16][sc + 0] = v.x;
        tile[rr + i * 16][sc + 1] = v.y;
        tile[rr + i * 16][sc + 2] = v.z;
        tile[rr + i * 16][sc + 3] = v.w;
    }
    __syncthreads();
    int ss = tid >> 3, rc = (tid & 7) * 8;
    #pragma unroll
    for (int i = 0; i < 2; ++i) {
        int sl = ss + i * 32;
        int sg = s0 + sl;
        int so = sg;
        if (fuse) {
            int half = (sg >= 3072) ? 1 : 0;
            int idx = sg - half * 3072;
            so = ((idx >> 4) << 5) | (half << 4) | (idx & 15);
        }
        bf16 tmp[8];
        #pragma unroll
        for (int j = 0; j < 8; ++j) tmp[j] = __float2bfloat16(tile[rc + j][sl]);
        *(uint4*)(out + mat + (size_t)so * R + r0 + rc) = *(uint4*)tmp;
    }
}

// gate: fp32 logits, sigmoid, top-4, normalize, build expert lists + token-major slots
__global__ void k_gate(const float* __restrict__ x, const float* __restrict__ wg,
                       const float* __restrict__ bias, int* __restrict__ cnt,
                       int* __restrict__ tok, float* __restrict__ wl,
                       int* __restrict__ slotk) {
    __shared__ float gates[16][17];
    int t = threadIdx.x;
    int tl = t >> 4;
    int e = t & 15;
    int token = blockIdx.x * 16 + tl;
    const float* xr = x + (size_t)token * 768;
    float acc = 0.f;
    #pragma unroll 4
    for (int c = 0; c < 768; ++c) acc += xr[c] * wg[c * 16 + e];
    acc += bias[e];
    gates[tl][e] = 1.f / (1.f + expf(-acc));
    __syncthreads();
    if (t < 16) {
        int token2 = blockIdx.x * 16 + t;
        float g[16];
        #pragma unroll
        for (int j = 0; j < 16; ++j) g[j] = gates[t][j];
        int idx[4]; float w[4]; float sum = 0.f;
        #pragma unroll
        for (int k = 0; k < 4; ++k) {
            float best = -1e30f; int bi = 0;
            #pragma unroll
            for (int j = 0; j < 16; ++j)
                if (g[j] > best) { best = g[j]; bi = j; }
            idx[k] = bi; w[k] = best; sum += best; g[bi] = -1e30f;
        }
        float inv = 1.f / sum;
        for (int k = 0; k < 4; ++k) {
            int slot = atomicAdd(&cnt[idx[k]], 1);
            tok[(idx[k] << 13) + slot] = token2;
            wl[(idx[k] << 13) + slot] = w[k] * inv;
            slotk[token2 * 4 + k] = (idx[k] << 13) | slot;
        }
    }
}

__global__ void k_offsets(const int* __restrict__ cnt, int* __restrict__ offs) {
    if (threadIdx.x == 0) {
        int s = 0;
        for (int e = 0; e < 16; ++e) { offs[e] = s; s += cnt[e]; }
    }
}

// combine: out[t] += sum_k routed[offs[e_k] + slot_k]   (weights applied in proj)
__global__ __launch_bounds__(192) void k_combine(
    const float* __restrict__ routed, const int* __restrict__ slotk,
    const int* __restrict__ offs, float* __restrict__ out) {
    int t = blockIdx.x;
    int c4 = threadIdx.x * 4;
    float* op = out + (size_t)t * 768 + c4;
    float4 acc = *(float4*)op;
    #pragma unroll
    for (int k = 0; k < 4; ++k) {
        int sk = slotk[t * 4 + k];
        int e = sk >> 13, sl = sk & 8191;
        const float* row = routed + (size_t)(offs[e] + sl) * 768 + c4;
        float4 v = *(const float4*)row;
        acc.x += v.x; acc.y += v.y; acc.z += v.z; acc.w += v.w;
    }
    *(float4*)op = acc;
}

// ---------------- unified 8-phase 256x256xBK64 GEMM core ----------------
// 8 waves (2M x 4N), per-wave 128x64. LDS 128 KiB = 2 buf x [A 256x64 | B 256x64].
// XOR swizzle: LDS dest linear (global_load_lds), inverse swizzle folded into the
// per-lane GLOBAL column (g0 = (tid&7)^(srow&7)), swizzled ds_read (swz0/swz1).
// All 8 stage loads issued at P0 (max slack ~3.75 phases); single vmcnt(0) at end
// of P3 (WAR on buffer nb is safe: its last reader finished before the barrier
// closing the previous tile). setprio(1) around each 16-MFMA cluster.
template<int KD>
__device__ __forceinline__ void gemm_core(
    const bf16* const* gA, const bf16* const* gB,
    bf16* lds, int tid, float4v (&acc)[8][4])
{
    constexpr int NT = KD / 64;
    int lane = tid & 63;
    int w = tid >> 6, wm = w & 1, wn = w >> 1;
    int quad = lane >> 4, l16 = lane & 15;
    int swz0 = ((quad    ) ^ (l16 & 7)) * 8;
    int swz1 = ((quad | 4) ^ (l16 & 7)) * 8;
    int aBase = wm * 8192 + l16 * 64;
    int bBase = 16384 + wn * 4096 + l16 * 64;

    auto stage = [&](int buf, int kt) {
        bf16* dB = lds + buf * 32768 + 16384;
        gload16(gB[0] + kt * 64, dB + tid * 8);
        gload16(gB[1] + kt * 64, dB + (tid + 512) * 8);
        gload16(gB[2] + kt * 64, dB + 8192 + tid * 8);
        gload16(gB[3] + kt * 64, dB + 8192 + (tid + 512) * 8);
        bf16* dA = lds + buf * 32768;
        gload16(gA[0] + kt * 64, dA + tid * 8);
        gload16(gA[1] + kt * 64, dA + (tid + 512) * 8);
        gload16(gA[2] + kt * 64, dA + 8192 + tid * 8);
        gload16(gA[3] + kt * 64, dA + 8192 + (tid + 512) * 8);
    };

    stage(0, 0);
    asm volatile("s_waitcnt vmcnt(0)" ::: "memory");   // prologue only
    BAR();

    for (int t = 0; t < NT; ++t) {
        const bf16* cb = lds + (t & 1) * 32768;
        short8 ar[4], br[4];

        // ---- P0: stage(t+1); ks=0, rows [0,64) ----
        if (t < NT - 1) stage((t & 1) ^ 1, t + 1);
        #pragma unroll
        for (int nf = 0; nf < 4; ++nf)
            br[nf] = *(const short8*)(cb + bBase + nf * 1024 + swz0);
        #pragma unroll
        for (int mf = 0; mf < 4; ++mf)
            ar[mf] = *(const short8*)(cb + aBase + mf * 1024 + swz0);
        __builtin_amdgcn_s_setprio(1);
        #pragma unroll
        for (int mf = 0; mf < 4; ++mf)
            #pragma unroll
            for (int nf = 0; nf < 4; ++nf)
                acc[mf][nf] = __builtin_amdgcn_mfma_f32_16x16x32_bf16(ar[mf], br[nf], acc[mf][nf], 0, 0, 0);
        __builtin_amdgcn_s_setprio(0);
        BAR();

        // ---- P1: ks=0, rows [64,128) ----
        #pragma unroll
        for (int mf = 0; mf < 4; ++mf)
            ar[mf] = *(const short8*)(cb + aBase + (mf + 4) * 1024 + swz0);
        __builtin_amdgcn_s_setprio(1);
        #pragma unroll
        for (int mf = 0; mf < 4; ++mf)
            #pragma unroll
            for (int nf = 0; nf < 4; ++nf)
                acc[mf + 4][nf] = __builtin_amdgcn_mfma_f32_16x16x32_bf16(ar[mf], br[nf], acc[mf + 4][nf], 0, 0, 0);
        __builtin_amdgcn_s_setprio(0);
        BAR();

        // ---- P2: ks=1, rows [0,64) ----
        #pragma unroll
        for (int nf = 0; nf < 4; ++nf)
            br[nf] = *(const short8*)(cb + bBase + nf * 1024 + swz1);
        #pragma unroll
        for (int mf = 0; mf < 4; ++mf)
            ar[mf] = *(const short8*)(cb + aBase + mf * 1024 + swz1);
        __builtin_amdgcn_s_setprio(1);
        #pragma unroll
        for (int mf = 0; mf < 4; ++mf)
            #pragma unroll
            for (int nf = 0; nf < 4; ++nf)
                acc[mf][nf] = __builtin_amdgcn_mfma_f32_16x16x32_bf16(ar[mf], br[nf], acc[mf][nf], 0, 0, 0);
        __builtin_amdgcn_s_setprio(0);
        BAR();

        // ---- P3: ks=1, rows [64,128) ; secure all of tile t+1 ----
        #pragma unroll
        for (int mf = 0; mf < 4; ++mf)
            ar[mf] = *(const short8*)(cb + aBase + (mf + 4) * 1024 + swz1);
        __builtin_amdgcn_s_setprio(1);
        #pragma unroll
        for (int mf = 0; mf < 4; ++mf)
            #pragma unroll
            for (int nf = 0; nf < 4; ++nf)
                acc[mf + 4][nf] = __builtin_amdgcn_mfma_f32_16x16x32_bf16(ar[mf], br[nf], acc[mf + 4][nf], 0, 0, 0);
        __builtin_amdgcn_s_setprio(0);
        asm volatile("s_waitcnt vmcnt(0)" ::: "memory");
        BAR();
    }
}

// ---------------- FC (shared = expert 16) with fused SwiGLU ----------------
// grid: (m-tiles=32, n-tiles=24, e=17). m on x so blocks sharing a B-panel are
// consecutive in dispatch -> B fetched from HBM once, rest L2/LLC hits.
__global__ __launch_bounds__(512) void k_fc(
    const bf16* __restrict__ A, const bf16* __restrict__ fcT, bf16* __restrict__ act,
    const int* __restrict__ cnt, const int* __restrict__ offs, const int* __restrict__ tok)
{
    const int Kd = 768;
    int e = blockIdx.z;
    int m0 = blockIdx.x * 256;
    int n0 = blockIdx.y * 256;
    int M; size_t actbase; const int* tl = nullptr;
    if (e == 16) {
        M = 8192; actbase = (size_t)32768 * 3072;
    } else {
        M = cnt[e];
        if (m0 >= M) return;
        tl = tok + (e << 13);
        actbase = (size_t)offs[e] * 3072;
    }
    const bf16* BT = fcT + (size_t)e * 6144 * Kd;

    __shared__ bf16 lds[65536];
    int tid = threadIdx.x;
    int srow = tid >> 3;
    int g0 = (tid & 7) ^ (srow & 7);

    const bf16* gA[4]; const bf16* gB[4];
    #pragma unroll
    for (int h = 0; h < 2; ++h) {
        int ra = m0 + h * 128 + srow;
        int a0 = tl ? tl[min(ra, M - 1)] : ra;
        int a1 = tl ? tl[min(ra + 64, M - 1)] : (ra + 64);
        gA[h * 2 + 0] = A + (size_t)a0 * Kd + g0 * 8;
        gA[h * 2 + 1] = A + (size_t)a1 * Kd + g0 * 8;
        gB[h * 2 + 0] = BT + (size_t)(n0 + h * 128 + srow) * Kd + g0 * 8;
        gB[h * 2 + 1] = BT + (size_t)(n0 + h * 128 + srow + 64) * Kd + g0 * 8;
    }

    float4v acc[8][4] = {};
    gemm_core<768>(gA, gB, lds, tid, acc);

    int lane = tid & 63, w = tid >> 6, wm = w & 1, wn = w >> 1;
    int quad = lane >> 4, l16 = lane & 15;
    int orow = m0 + wm * 128;
    int ocol = (n0 + wn * 64) >> 1;
    #pragma unroll
    for (int mf = 0; mf < 8; ++mf)
        #pragma unroll
        for (int j = 0; j < 2; ++j)
            #pragma unroll
            for (int r = 0; r < 4; ++r) {
                int mrow = orow + mf * 16 + quad * 4 + r;
                if (tl && mrow >= M) continue;
                int col = ocol + j * 16 + l16;
                float g = acc[mf][2 * j][r];
                float v = acc[mf][2 * j + 1][r];
                float sg = g / (1.f + __expf(-g));
                act[actbase + (size_t)mrow * 3072 + col] = __float2bfloat16(sg * v);
            }
}

// ---------------- Proj (shared = expert 16) ----------------
// grid: (m-tiles=32, n-tiles=3, e=17). routed -> routed_out (xwl), shared -> out.
__global__ __launch_bounds__(512) void k_proj(
    const bf16* __restrict__ act, const bf16* __restrict__ prT,
    float* __restrict__ out, float* __restrict__ routed_out,
    const int* __restrict__ cnt, const int* __restrict__ offs, const float* __restrict__ wl)
{
    const int Kd = 3072;
    int e = blockIdx.z;
    int m0 = blockIdx.x * 256;
    int n0 = blockIdx.y * 256;
    int M; size_t abase; int roffs = 0;
    bool rt = (e != 16);
    if (rt) {
        M = cnt[e];
        if (m0 >= M) return;
        roffs = offs[e];
        abase = (size_t)roffs * Kd;
    } else {
        M = 8192; abase = (size_t)32768 * Kd;
    }
    const bf16* BT = prT + (size_t)e * 768 * Kd;

    __shared__ bf16 lds[65536];
    int tid = threadIdx.x;
    int srow = tid >> 3;
    int g0 = (tid & 7) ^ (srow & 7);

    const bf16* gA[4]; const bf16* gB[4];
    #pragma unroll
    for (int h = 0; h < 2; ++h) {
        int ra = m0 + h * 128 + srow;
        int a0 = rt ? min(ra, M - 1) : ra;
        int a1 = rt ? min(ra + 64, M - 1) : (ra + 64);
        gA[h * 2 + 0] = act + abase + (size_t)a0 * Kd + g0 * 8;
        gA[h * 2 + 1] = act + abase + (size_t)a1 * Kd + g0 * 8;
        gB[h * 2 + 0] = BT + (size_t)(n0 + h * 128 + srow) * Kd + g0 * 8;
        gB[h * 2 + 1] = BT + (size_t)(n0 + h * 128 + srow + 64) * Kd + g0 * 8;
    }

    float4v acc[8][4] = {};
    gemm_core<3072>(gA, gB, lds, tid, acc);

    int lane = tid & 63, w = tid >> 6, wm = w & 1, wn = w >> 1;
    int quad = lane >> 4, l16 = lane & 15;
    int orow = m0 + wm * 128;
    int ocol = n0 + wn * 64;
    #pragma unroll
    for (int mf = 0; mf < 8; ++mf)
        #pragma unroll
        for (int r = 0; r < 4; ++r) {
            int mr = orow + mf * 16 + quad * 4 + r;
            if (rt) {
                if (mr >= M) continue;
                float wgt = wl[(e << 13) + mr];
                float* orowp = routed_out + (size_t)(roffs + mr) * 768;
                #pragma unroll
                for (int nf = 0; nf < 4; ++nf)
                    orowp[ocol + nf * 16 + l16] = wgt * acc[mf][nf][r];
            } else {
                float* orowp = out + (size_t)mr * 768;
                #pragma unroll
                for (int nf = 0; nf < 4; ++nf)
                    orowp[ocol + nf * 16 + l16] = acc[mf][nf][r];
            }
        }
}

// ---------------- launch ----------------

extern "C" void kernel_launch(void* const* d_in, const int* in_sizes, int n_in,
                              void* d_out, int out_size, void* d_ws, size_t ws_size,
                              hipStream_t stream) {
    const float* x    = (const float*)d_in[0];
    const float* wfc  = (const float*)d_in[1];
    const float* wpr  = (const float*)d_in[2];
    const float* wefc = (const float*)d_in[3];
    const float* wepr = (const float*)d_in[4];
    const float* wg   = (const float*)d_in[5];
    const float* eb   = (const float*)d_in[6];
    float* out = (float*)d_out;

    char* p = (char*)d_ws;
    bf16* x_bf  = (bf16*)p; p += (size_t)8192 * 768 * 2;            // 12.6 MB
    bf16* fcT   = (bf16*)p; p += (size_t)17 * 6144 * 768 * 2;       // 160.4 MB (slot16=shared)
    bf16* prT   = (bf16*)p; p += (size_t)17 * 768 * 3072 * 2;       // 80.2 MB
    bf16* act   = (bf16*)p; p += (size_t)40960 * 3072 * 2;          // 251.7 MB (routed rows 0..32767, shared 32768..40959)
    int* cnt    = (int*)p;  p += 64;
    int* offs   = (int*)p;  p += 64;
    int* tok    = (int*)p;  p += (size_t)16 * 8192 * 4;
    float* wl   = (float*)p; p += (size_t)16 * 8192 * 4;
    int* slotk  = (int*)p;  p += (size_t)8192 * 4 * 4;
    float* routed_out = (float*)fcT;   // fcT dead after k_fc (160.4 MB >= 100.7 MB)

    k_convert_x<<<dim3(6144), dim3(256), 0, stream>>>(x, x_bf, 8192 * 768, cnt);
    k_transpose64<<<dim3(96, 12, 16), dim3(256), 0, stream>>>(wefc, fcT, 768, 6144, 1);
    k_transpose64<<<dim3(96, 12, 1), dim3(256), 0, stream>>>(wfc, fcT + (size_t)16 * 6144 * 768, 768, 6144, 1);
    k_transpose64<<<dim3(12, 48, 16), dim3(256), 0, stream>>>(wepr, prT, 3072, 768, 0);
    k_transpose64<<<dim3(12, 48, 1), dim3(256), 0, stream>>>(wpr, prT + (size_t)16 * 768 * 3072, 3072, 768, 0);
    k_gate<<<dim3(512), dim3(256), 0, stream>>>(x, wg, eb, cnt, tok, wl, slotk);
    k_offsets<<<dim3(1), dim3(64), 0, stream>>>(cnt, offs);

    k_fc<<<dim3(32, 24, 17), dim3(512), 0, stream>>>(x_bf, fcT, act, cnt, offs, tok);
    k_proj<<<dim3(32, 3, 17), dim3(512), 0, stream>>>(act, prT, out, routed_out, cnt, offs, wl);
    k_combine<<<dim3(8192), dim3(192), 0, stream>>>(routed_out, slotk, offs, out);
}